// Round 12
// baseline (1196.221 us; speedup 1.0000x reference)
//
#include <hip/hip_runtime.h>
#include <math.h>

// ---------------------------------------------------------------------------
// RetentionBlock: LN1 -> QKVG proj -> retention scan -> Wo + residual ->
//                 LN2 -> FFN(gelu) + residual
// B=4, L=4096, D_MODEL=1024, H=16, DH=64. All global inputs f32.
// R20 == R19 resubmit (round-11 bench was an infra failure: container died
//     before dispatch; identical precedent in round 2 resolved on resubmit).
// R19 = R18 (892.1us, tie-best) + ONE gemm lever: __launch_bounds__(256,5).
//     Counters: occupancy 42% (~3.4 blocks/CU) with VGPR=56 and LDS=32KB
//     -> 5 blocks/CU fits exactly (5x32KB = 160KB pool; reg budget 102).
//     The gemm stall is the per-iter barrier drain; blocks are barrier-
//     independent, so +25% resident blocks covers the drain with other
//     blocks' MFMA waves (m114 co-scheduling). R8's own history: 3->4
//     blocks/CU was its winning lever; this is the next step.
//     Everything else byte-identical to R18.
// ---------------------------------------------------------------------------

#define D_MODEL 1024
#define LSEQ    4096
#define BATCH   4
#define NROWS   (BATCH * LSEQ)      // 16384
#define HEADS   16
#define DH      64
#define CHUNK   64
#define NCH     (LSEQ / CHUNK)      // 64

typedef short  short8  __attribute__((ext_vector_type(8)));
typedef short  short4v __attribute__((ext_vector_type(4)));
typedef float  float4v __attribute__((ext_vector_type(4)));

__device__ inline short f2bf(float f) {
    unsigned u = __float_as_uint(f);
    u += 0x7fffu + ((u >> 16) & 1u);   // round-to-nearest-even
    return (short)(u >> 16);
}
__device__ inline float bf2f(short s) {
    return __uint_as_float(((unsigned)(unsigned short)s) << 16);
}

// async global->LDS, 16 bytes per lane; dest = wave-uniform base + lane*16
__device__ inline void load_lds16(const short* g, short* l) {
    __builtin_amdgcn_global_load_lds(
        (const __attribute__((address_space(1))) void*)g,
        (__attribute__((address_space(3))) void*)l,
        16, 0, 0);
}

// ---------------------------------------------------------------------------
// Fused prep + LN1, ONE launch, 1024 thr/block. Flat grid 4356:
//   [0,1280):    5 square 1024x1024 transposes, 64x64 tiles (256 each)
//   [1280,2304): W1 1024x4096 -> W1T (bx<64, by<16)
//   [2304,3328): W2 4096x1024 -> W2T (bx<16, by<64)
//   [3328,3332): bias concat bq|bk|bv|bg -> biasq[4096]
//   [3332,4356): LN1 (16 waves = 16 rows/block), x -> ybuf(bf16)
// ---------------------------------------------------------------------------
__global__ __launch_bounds__(1024) void prep_ln1(
    const float* __restrict__ Wq, const float* __restrict__ Wk,
    const float* __restrict__ Wv, const float* __restrict__ Wg,
    const float* __restrict__ Wo, const float* __restrict__ W1,
    const float* __restrict__ W2,
    const float* __restrict__ bq, const float* __restrict__ bk,
    const float* __restrict__ bv, const float* __restrict__ bg,
    const float* __restrict__ x, const float* __restrict__ g1,
    const float* __restrict__ b1v,
    short* __restrict__ WqkvgT, short* __restrict__ WoT,
    short* __restrict__ W1T, short* __restrict__ W2T,
    float* __restrict__ biasq, short* __restrict__ ybuf)
{
    const int bid = blockIdx.x;
    const int tid = threadIdx.x;

    if (bid >= 3332) {                   // ---- LN1: wave-per-row ----
        const int wave = tid >> 6, lane = tid & 63;
        const int row  = (bid - 3332) * 16 + wave;
        const float4* xr = (const float4*)(x + (size_t)row * D_MODEL);
        float4 v[4];
        float s = 0.0f, ss = 0.0f;
        #pragma unroll
        for (int qq = 0; qq < 4; qq++) {
            v[qq] = xr[lane + qq * 64];
            s  += v[qq].x + v[qq].y + v[qq].z + v[qq].w;
            ss += v[qq].x * v[qq].x + v[qq].y * v[qq].y
                + v[qq].z * v[qq].z + v[qq].w * v[qq].w;
        }
        #pragma unroll
        for (int off = 32; off > 0; off >>= 1) {
            s  += __shfl_xor(s, off);
            ss += __shfl_xor(ss, off);
        }
        const float mu  = s * (1.0f / D_MODEL);
        const float var = ss * (1.0f / D_MODEL) - mu * mu;
        const float rs  = rsqrtf(var + 1e-5f);
        short4v* yr = (short4v*)(ybuf + (size_t)row * D_MODEL);
        #pragma unroll
        for (int qq = 0; qq < 4; qq++) {
            const float4 gg = ((const float4*)g1)[lane + qq * 64];
            const float4 bb = ((const float4*)b1v)[lane + qq * 64];
            short4v o;
            o.x = f2bf((v[qq].x - mu) * rs * gg.x + bb.x);
            o.y = f2bf((v[qq].y - mu) * rs * gg.y + bb.y);
            o.z = f2bf((v[qq].z - mu) * rs * gg.z + bb.z);
            o.w = f2bf((v[qq].w - mu) * rs * gg.w + bb.w);
            yr[lane + qq * 64] = o;
        }
        return;
    }

    if (bid >= 3328) {                   // ---- bias concat ----
        int i = (bid - 3328) * 1024 + tid;
        const float* src = (i < 1024) ? bq : (i < 2048) ? bk
                         : (i < 3072) ? bv : bg;
        biasq[i] = src[i & 1023];
        return;
    }

    // ---- transposes f32 [R][C] -> bf16 [C][R], 64x64 tile, 4 elem/thr ----
    const int tx = tid & 63, ty = tid >> 6;     // ty in [0,16)
    const float* src; short* dst; int R, C, bx, by;
    if (bid < 1280) {                    // square 1024x1024
        const int m = bid >> 8, t = bid & 255;
        bx = t & 15; by = t >> 4; R = 1024; C = 1024;
        if (m < 4) { src = (m == 0) ? Wq : (m == 1) ? Wk : (m == 2) ? Wv : Wg;
                     dst = WqkvgT + (size_t)m * 1024 * 1024; }
        else       { src = Wo; dst = WoT; }
    } else if (bid < 2304) {             // W1: R=1024, C=4096
        const int t = bid - 1280;
        bx = t & 63; by = t >> 6; R = 1024; C = 4096;
        src = W1; dst = W1T;
    } else {                             // W2: R=4096, C=1024
        const int t = bid - 2304;
        bx = t & 15; by = t >> 4; R = 4096; C = 1024;
        src = W2; dst = W2T;
    }

    __shared__ float tile[64][65];
    const int r0 = by * 64, c0 = bx * 64;
    #pragma unroll
    for (int i = 0; i < 4; i++)
        tile[ty + 16 * i][tx] = src[(size_t)(r0 + ty + 16 * i) * C + c0 + tx];
    __syncthreads();
    #pragma unroll
    for (int i = 0; i < 4; i++)
        dst[(size_t)(c0 + ty + 16 * i) * R + r0 + tx] =
            f2bf(tile[tx][ty + 16 * i]);
}

// ---------------------------------------------------------------------------
// Row LayerNorm, wave-per-row: f32 [row][1024] -> bf16 [row][1024].
// 256 thr = 4 waves = 4 rows/block; no __syncthreads; shfl_xor reduce.
// ---------------------------------------------------------------------------
__global__ __launch_bounds__(256) void ln_kernel(
    const float* __restrict__ x, const float* __restrict__ g,
    const float* __restrict__ b, short* __restrict__ y)
{
    const int wave = threadIdx.x >> 6, lane = threadIdx.x & 63;
    const int row  = blockIdx.x * 4 + wave;
    const float4* xr = (const float4*)(x + (size_t)row * D_MODEL);
    float4 v[4];
    float s = 0.0f, ss = 0.0f;
    #pragma unroll
    for (int qq = 0; qq < 4; qq++) {
        v[qq] = xr[lane + qq * 64];
        s  += v[qq].x + v[qq].y + v[qq].z + v[qq].w;
        ss += v[qq].x * v[qq].x + v[qq].y * v[qq].y
            + v[qq].z * v[qq].z + v[qq].w * v[qq].w;
    }
    #pragma unroll
    for (int off = 32; off > 0; off >>= 1) {
        s  += __shfl_xor(s, off);
        ss += __shfl_xor(ss, off);
    }
    const float mu  = s * (1.0f / D_MODEL);
    const float var = ss * (1.0f / D_MODEL) - mu * mu;
    const float rs  = rsqrtf(var + 1e-5f);
    short4v* yr = (short4v*)(y + (size_t)row * D_MODEL);
    #pragma unroll
    for (int qq = 0; qq < 4; qq++) {
        const float4 gg = ((const float4*)g)[lane + qq * 64];
        const float4 bb = ((const float4*)b)[lane + qq * 64];
        short4v o;
        o.x = f2bf((v[qq].x - mu) * rs * gg.x + bb.x);
        o.y = f2bf((v[qq].y - mu) * rs * gg.y + bb.y);
        o.z = f2bf((v[qq].z - mu) * rs * gg.z + bb.z);
        o.w = f2bf((v[qq].w - mu) * rs * gg.w + bb.w);
        yr[lane + qq * 64] = o;
    }
}

// ---------------------------------------------------------------------------
// bf16 MFMA GEMM: C[M][N] = A[M][K](bf16) * BT[N][K](bf16)^T, fused epilogue.
// Block 256 = 4 waves; tile 128x128; wave owns 64x64 as 4x4 of 16x16x32 MFMA.
// Staging: global_load_lds width=16, double-buffered LDS, 1 barrier/iter.
// LDS slot map (16B units): slot(row, q) = row*4 + (q ^ ((row>>1)&3)).
// Grid swizzle: windows of 8 x-blocks, y fastest (R4 measured-best).
// __launch_bounds__(256,5): 5 blocks/CU (VGPR 56 < 102 budget; LDS 5x32KB
// = 160KB pool exactly) -> +25% resident waves to cover the barrier drain.
// mode 0: out_bf16 = (col>=3072 ? sigmoid : id)(acc + bias)        [QKVG]
// mode 1: out_f32  = acc + bias + res   (res==outf in-place is OK) [x2 / final]
// mode 2: out_bf16 = gelu_exact(acc + bias)                        [FFN mid]
// ---------------------------------------------------------------------------
__global__ __launch_bounds__(256, 5) void gemm_bf16(
    const short* __restrict__ A, const short* __restrict__ BT,
    const float* __restrict__ bias, const float* __restrict__ res,
    float* __restrict__ outf, short* __restrict__ outb,
    int M, int N, int K, int mode)
{
    __shared__ short As[2 * 4096];   // 2 x 8 KB, slot-swizzled
    __shared__ short Bs[2 * 4096];

    // ---- grid swizzle: window = 8 x-values * all y, y fastest inside ----
    const int gx = gridDim.x, gy = gridDim.y;
    const int lin = blockIdx.x + blockIdx.y * gx;
    const int win = 8 * gy;
    const int grp = lin / win;
    const int rem = lin - grp * win;
    const int bx = grp * 8 + (rem & 7);
    const int by = rem >> 3;

    const int tid  = threadIdx.x;
    const int row0 = bx * 128;
    const int col0 = by * 128;
    const int lane = tid & 63;
    const int wave = tid >> 6;
    const int wm = (wave & 1) << 6;
    const int wn = (wave >> 1) << 6;
    const int lm = lane & 15;            // m / n index within 16-tile
    const int q  = lane >> 4;            // kgroup 0..3 of this lane's fragment

    float4v acc[4][4];
    #pragma unroll
    for (int i = 0; i < 4; i++)
        #pragma unroll
        for (int j = 0; j < 4; j++)
            acc[i][j] = (float4v)(0.0f);

    // ---- staging decode (constant per lane; only k0 varies) ----
    const int s0 = wave * 64 + lane;
    const int s1 = 256 + wave * 64 + lane;
    const int r0 = s0 >> 2, q0 = (s0 & 3) ^ ((r0 >> 1) & 3);
    const int r1 = s1 >> 2, q1 = (s1 & 3) ^ ((r1 >> 1) & 3);
    const short* gA0 = A  + (size_t)(row0 + r0) * K + q0 * 8;
    const short* gA1 = A  + (size_t)(row0 + r1) * K + q1 * 8;
    const short* gB0 = BT + (size_t)(col0 + r0) * K + q0 * 8;
    const short* gB1 = BT + (size_t)(col0 + r1) * K + q1 * 8;
    short* lA0 = As + s0 * 8;
    short* lA1 = As + s1 * 8;
    short* lB0 = Bs + s0 * 8;
    short* lB1 = Bs + s1 * 8;

    // fragment-read swizzle: row = 16*t + lm  ->  (row>>1)&3 == (lm>>1)&3
    const int swz = (lm >> 1) & 3;
    const int qs  = q ^ swz;             // swizzled kgroup slot for reads

    // prologue: tile 0 -> buffer 0
    load_lds16(gA0, lA0);
    load_lds16(gA1, lA1);
    load_lds16(gB0, lB0);
    load_lds16(gB1, lB1);

    int p = 0;
    for (int k0 = 0; k0 < K; k0 += 32) {
        __syncthreads();                 // drains this tile's loads + prior reads
        const int kn = k0 + 32;
        const int po = p ^ 1;
        if (kn < K) {                    // prefetch next tile into other buffer
            load_lds16(gA0 + kn, lA0 + po * 4096);
            load_lds16(gA1 + kn, lA1 + po * 4096);
            load_lds16(gB0 + kn, lB0 + po * 4096);
            load_lds16(gB1 + kn, lB1 + po * 4096);
        }
        const short* Ab = As + p * 4096;
        const short* Bb = Bs + p * 4096;

        short8 af[4], bfr[4];
        #pragma unroll
        for (int i = 0; i < 4; i++)
            af[i] = *(const short8*)&Ab[((wm + i * 16 + lm) * 4 + qs) * 8];
        #pragma unroll
        for (int j = 0; j < 4; j++)
            bfr[j] = *(const short8*)&Bb[((wn + j * 16 + lm) * 4 + qs) * 8];
        #pragma unroll
        for (int i = 0; i < 4; i++)
            #pragma unroll
            for (int j = 0; j < 4; j++)
                acc[i][j] = __builtin_amdgcn_mfma_f32_16x16x32_bf16(
                    af[i], bfr[j], acc[i][j], 0, 0, 0);
        p ^= 1;
    }

    const int r4 = (lane >> 4) << 2;     // C/D: row=(lane>>4)*4+reg, col=lane&15
    #pragma unroll
    for (int i = 0; i < 4; i++) {
        #pragma unroll
        for (int j = 0; j < 4; j++) {
            int colg = col0 + wn + j * 16 + lm;
            float bcol = bias[colg];
            #pragma unroll
            for (int r2 = 0; r2 < 4; r2++) {
                int rowg = row0 + wm + i * 16 + r4 + r2;
                size_t idx = (size_t)rowg * N + colg;
                float v = acc[i][j][r2] + bcol;
                if (mode == 0) {
                    if (colg >= 3072) v = 1.0f / (1.0f + expf(-v));
                    outb[idx] = f2bf(v);
                } else if (mode == 1) {
                    outf[idx] = v + res[idx];
                } else {
                    v = 0.5f * v * (1.0f + erff(v * 0.70710678118654752f));
                    outb[idx] = f2bf(v);
                }
            }
        }
    }
}

// ---------------------------------------------------------------------------
// Retention scan, short2-vectorized (2 channels/thread), CHUNK=64.
// qkvg bf16 [16384][4096]: q|k|v|g sections. channel c = b*1024 + col.
// 512 blocks x 256 thr per pass (TLP preserved); 4B/lane loads.
// pass2 computes sinit inline (Horner over carry[0..j-1]).
// ---------------------------------------------------------------------------
__global__ __launch_bounds__(256) void scan_pass1(
    const short* __restrict__ qkvg, const float* __restrict__ dlogit,
    float* __restrict__ carry)
{
    const int j    = blockIdx.x >> 3;                       // chunk 0..63
    const int p    = ((blockIdx.x & 7) << 8) + threadIdx.x; // 0..2047
    const int col2 = p << 1;
    const int b    = col2 >> 10;
    const int col  = col2 & 1023;
    const float decay = 1.0f / (1.0f + expf(-dlogit[col >> 6]));
    size_t base = ((size_t)b * LSEQ + j * CHUNK) * 4096 + col;
    float s0 = 0.0f, s1 = 0.0f;
    for (int t = 0; t < CHUNK; ++t) {
        short2 kk = *(const short2*)&qkvg[base + 1024];
        short2 vv = *(const short2*)&qkvg[base + 2048];
        s0 = decay * s0 + bf2f(kk.x) * bf2f(vv.x);
        s1 = decay * s1 + bf2f(kk.y) * bf2f(vv.y);
        base += 4096;
    }
    *(float2*)&carry[j * 4096 + col2] = make_float2(s0, s1);
}

__global__ __launch_bounds__(256) void scan_pass2(
    const short* __restrict__ qkvg, const float* __restrict__ dlogit,
    const float* __restrict__ carry, short* __restrict__ att)
{
    const int j    = blockIdx.x >> 3;
    const int p    = ((blockIdx.x & 7) << 8) + threadIdx.x;
    const int col2 = p << 1;
    const int b    = col2 >> 10;
    const int col  = col2 & 1023;
    const float decay = 1.0f / (1.0f + expf(-dlogit[col >> 6]));
    const float dp = powf(decay, (float)CHUNK);
    float s0 = 0.0f, s1 = 0.0f;
    for (int i = 0; i < j; ++i) {        // inline sinit (Horner, same order)
        float2 cc = *(const float2*)&carry[i * 4096 + col2];
        s0 = dp * s0 + cc.x;
        s1 = dp * s1 + cc.y;
    }
    size_t base  = ((size_t)b * LSEQ + j * CHUNK) * 4096 + col;
    size_t obase = ((size_t)b * LSEQ + j * CHUNK) * 1024 + col;
    for (int t = 0; t < CHUNK; ++t) {
        short2 qq = *(const short2*)&qkvg[base];
        short2 kk = *(const short2*)&qkvg[base + 1024];
        short2 vv = *(const short2*)&qkvg[base + 2048];
        short2 gg = *(const short2*)&qkvg[base + 3072];
        s0 = decay * s0 + bf2f(kk.x) * bf2f(vv.x);
        s1 = decay * s1 + bf2f(kk.y) * bf2f(vv.y);
        short2 o;
        o.x = f2bf(bf2f(gg.x) * bf2f(qq.x) * s0 * 0.125f);  // scale = DH^-0.5
        o.y = f2bf(bf2f(gg.y) * bf2f(qq.y) * s1 * 0.125f);
        *(short2*)&att[obase] = o;
        base += 4096; obase += 1024;
    }
}

// ---------------------------------------------------------------------------
extern "C" void kernel_launch(void* const* d_in, const int* in_sizes, int n_in,
                              void* d_out, int out_size, void* d_ws, size_t ws_size,
                              hipStream_t stream)
{
    const float* x      = (const float*)d_in[0];
    const float* ln1_g  = (const float*)d_in[1];
    const float* ln1_b  = (const float*)d_in[2];
    const float* Wq     = (const float*)d_in[3];
    const float* bq     = (const float*)d_in[4];
    const float* Wk     = (const float*)d_in[5];
    const float* bk     = (const float*)d_in[6];
    const float* Wv     = (const float*)d_in[7];
    const float* bv     = (const float*)d_in[8];
    const float* Wg     = (const float*)d_in[9];
    const float* bg     = (const float*)d_in[10];
    const float* dlog   = (const float*)d_in[11];
    const float* Wo     = (const float*)d_in[12];
    const float* bo     = (const float*)d_in[13];
    const float* ln2_g  = (const float*)d_in[14];
    const float* ln2_b  = (const float*)d_in[15];
    const float* W1     = (const float*)d_in[16];
    const float* b1     = (const float*)d_in[17];
    const float* W2     = (const float*)d_in[18];
    const float* b2     = (const float*)d_in[19];
    float* out = (float*)d_out;

    char* ws = (char*)d_ws;
    size_t off = 0;
    auto alloc = [&](size_t bytes) -> void* {
        void* p = ws + off;
        off += (bytes + 255) & ~(size_t)255;
        return p;
    };
    // ---- workspace layout (~196 MB total) ----
    short* WqkvgT = (short*)alloc((size_t)4096 * 1024 * 2);   // 8 MB  [n=4096][k=1024]
    short* WoT    = (short*)alloc((size_t)1024 * 1024 * 2);   // 2 MB  [n=1024][k=1024]
    short* W1T    = (short*)alloc((size_t)4096 * 1024 * 2);   // 8 MB  [n=4096][k=1024]
    short* W2T    = (short*)alloc((size_t)1024 * 4096 * 2);   // 8 MB  [n=1024][k=4096]
    float* biasq  = (float*)alloc((size_t)4096 * 4);
    float* carry  = (float*)alloc((size_t)NCH * 4096 * 4);    // 1 MB
    short* bufA   = (short*)alloc((size_t)NROWS * 1024 * 2);  // 32 MB: y -> att -> h
    short* bufB   = (short*)alloc((size_t)NROWS * 4096 * 2);  // 128 MB: qkvg -> ff1
    // x2 lives in d_out (64 MB saved); final GEMM does in-place residual.
    float* x2 = out;
    short* ybuf = bufA;   // LN1 output
    short* att  = bufA;   // scan output (ybuf dead by then)
    short* hbuf = bufA;   // LN2 output (att dead by then)
    short* qkvg = bufB;
    short* ff1  = bufB;   // qkvg dead after scan_pass2
    (void)in_sizes; (void)n_in; (void)out_size;

    if (off > ws_size) return;  // ws too small: fail validation cleanly, not a segfault

    // prep (7 transposes + bias concat) + LN1 in ONE launch
    prep_ln1<<<4356, 1024, 0, stream>>>(
        Wq, Wk, Wv, Wg, Wo, W1, W2, bq, bk, bv, bg,
        x, ln1_g, ln1_b,
        WqkvgT, WoT, W1T, W2T, biasq, ybuf);

    // QKVG projection (fused bias + sigmoid on G)
    gemm_bf16<<<dim3(128, 32), 256, 0, stream>>>(
        ybuf, WqkvgT, biasq, nullptr, nullptr, qkvg, NROWS, 4096, 1024, 0);

    // retention scan (short2, CHUNK=64; combine folded into pass2)
    scan_pass1<<<NCH * 8, 256, 0, stream>>>(qkvg, dlog, carry);
    scan_pass2<<<NCH * 8, 256, 0, stream>>>(qkvg, dlog, carry, att);

    // output projection + residual: x2 = x + att@Wo + bo   (x2 == d_out)
    gemm_bf16<<<dim3(128, 8), 256, 0, stream>>>(
        att, WoT, bo, x, x2, nullptr, NROWS, 1024, 1024, 1);

    // LN2: x2 -> h(bf16)
    ln_kernel<<<NROWS / 4, 256, 0, stream>>>(x2, ln2_g, ln2_b, hbuf);

    // FFN: ff1 = gelu(h@W1 + b1)  (bf16)
    gemm_bf16<<<dim3(128, 32), 256, 0, stream>>>(
        hbuf, W1T, b1, nullptr, nullptr, ff1, NROWS, 4096, 1024, 2);

    // out = x2 + ff1@W2 + b2   (in-place residual on d_out)
    gemm_bf16<<<dim3(128, 8), 256, 0, stream>>>(
        ff1, W2T, b2, x2, out, nullptr, NROWS, 1024, 4096, 1);
}

// Round 13
// 887.183 us; speedup vs baseline: 1.3483x; 1.3483x over previous
//
#include <hip/hip_runtime.h>
#include <math.h>

// ---------------------------------------------------------------------------
// RetentionBlock: LN1 -> QKVG proj -> retention scan -> Wo + residual ->
//                 LN2 -> FFN(gelu) + residual
// B=4, L=4096, D_MODEL=1024, H=16, DH=64. All global inputs f32.
// R21 == R18 byte-exact revert (measured best: 892.1us).
// R20's (256,5) FAILED: allocator squeezed VGPR 56->48, WRITE_SIZE doubled
//     (scratch spill traffic), occupancy barely moved (LDS pool never
//     admitted the 5th block) -> gemm 230->322us. Lesson: a tighter
//     waves/EU bound constrains the register allocator even when the
//     extra block never materializes.
// Ledger: 7 gemm structural variants (R9/R11/R12/R13/R14/R16/R20) all
//     regressed vs the 2-phase 128^2 loop at 226-230us (m233 ceiling);
//     non-gemm wins harvested (R15 +27us, R18 +14us). R18 is the
//     empirical optimum of this kernel family.
// ---------------------------------------------------------------------------

#define D_MODEL 1024
#define LSEQ    4096
#define BATCH   4
#define NROWS   (BATCH * LSEQ)      // 16384
#define HEADS   16
#define DH      64
#define CHUNK   64
#define NCH     (LSEQ / CHUNK)      // 64

typedef short  short8  __attribute__((ext_vector_type(8)));
typedef short  short4v __attribute__((ext_vector_type(4)));
typedef float  float4v __attribute__((ext_vector_type(4)));

__device__ inline short f2bf(float f) {
    unsigned u = __float_as_uint(f);
    u += 0x7fffu + ((u >> 16) & 1u);   // round-to-nearest-even
    return (short)(u >> 16);
}
__device__ inline float bf2f(short s) {
    return __uint_as_float(((unsigned)(unsigned short)s) << 16);
}

// async global->LDS, 16 bytes per lane; dest = wave-uniform base + lane*16
__device__ inline void load_lds16(const short* g, short* l) {
    __builtin_amdgcn_global_load_lds(
        (const __attribute__((address_space(1))) void*)g,
        (__attribute__((address_space(3))) void*)l,
        16, 0, 0);
}

// ---------------------------------------------------------------------------
// Fused prep + LN1, ONE launch, 1024 thr/block. Flat grid 4356:
//   [0,1280):    5 square 1024x1024 transposes, 64x64 tiles (256 each)
//   [1280,2304): W1 1024x4096 -> W1T (bx<64, by<16)
//   [2304,3328): W2 4096x1024 -> W2T (bx<16, by<64)
//   [3328,3332): bias concat bq|bk|bv|bg -> biasq[4096]
//   [3332,4356): LN1 (16 waves = 16 rows/block), x -> ybuf(bf16)
// ---------------------------------------------------------------------------
__global__ __launch_bounds__(1024) void prep_ln1(
    const float* __restrict__ Wq, const float* __restrict__ Wk,
    const float* __restrict__ Wv, const float* __restrict__ Wg,
    const float* __restrict__ Wo, const float* __restrict__ W1,
    const float* __restrict__ W2,
    const float* __restrict__ bq, const float* __restrict__ bk,
    const float* __restrict__ bv, const float* __restrict__ bg,
    const float* __restrict__ x, const float* __restrict__ g1,
    const float* __restrict__ b1v,
    short* __restrict__ WqkvgT, short* __restrict__ WoT,
    short* __restrict__ W1T, short* __restrict__ W2T,
    float* __restrict__ biasq, short* __restrict__ ybuf)
{
    const int bid = blockIdx.x;
    const int tid = threadIdx.x;

    if (bid >= 3332) {                   // ---- LN1: wave-per-row ----
        const int wave = tid >> 6, lane = tid & 63;
        const int row  = (bid - 3332) * 16 + wave;
        const float4* xr = (const float4*)(x + (size_t)row * D_MODEL);
        float4 v[4];
        float s = 0.0f, ss = 0.0f;
        #pragma unroll
        for (int qq = 0; qq < 4; qq++) {
            v[qq] = xr[lane + qq * 64];
            s  += v[qq].x + v[qq].y + v[qq].z + v[qq].w;
            ss += v[qq].x * v[qq].x + v[qq].y * v[qq].y
                + v[qq].z * v[qq].z + v[qq].w * v[qq].w;
        }
        #pragma unroll
        for (int off = 32; off > 0; off >>= 1) {
            s  += __shfl_xor(s, off);
            ss += __shfl_xor(ss, off);
        }
        const float mu  = s * (1.0f / D_MODEL);
        const float var = ss * (1.0f / D_MODEL) - mu * mu;
        const float rs  = rsqrtf(var + 1e-5f);
        short4v* yr = (short4v*)(ybuf + (size_t)row * D_MODEL);
        #pragma unroll
        for (int qq = 0; qq < 4; qq++) {
            const float4 gg = ((const float4*)g1)[lane + qq * 64];
            const float4 bb = ((const float4*)b1v)[lane + qq * 64];
            short4v o;
            o.x = f2bf((v[qq].x - mu) * rs * gg.x + bb.x);
            o.y = f2bf((v[qq].y - mu) * rs * gg.y + bb.y);
            o.z = f2bf((v[qq].z - mu) * rs * gg.z + bb.z);
            o.w = f2bf((v[qq].w - mu) * rs * gg.w + bb.w);
            yr[lane + qq * 64] = o;
        }
        return;
    }

    if (bid >= 3328) {                   // ---- bias concat ----
        int i = (bid - 3328) * 1024 + tid;
        const float* src = (i < 1024) ? bq : (i < 2048) ? bk
                         : (i < 3072) ? bv : bg;
        biasq[i] = src[i & 1023];
        return;
    }

    // ---- transposes f32 [R][C] -> bf16 [C][R], 64x64 tile, 4 elem/thr ----
    const int tx = tid & 63, ty = tid >> 6;     // ty in [0,16)
    const float* src; short* dst; int R, C, bx, by;
    if (bid < 1280) {                    // square 1024x1024
        const int m = bid >> 8, t = bid & 255;
        bx = t & 15; by = t >> 4; R = 1024; C = 1024;
        if (m < 4) { src = (m == 0) ? Wq : (m == 1) ? Wk : (m == 2) ? Wv : Wg;
                     dst = WqkvgT + (size_t)m * 1024 * 1024; }
        else       { src = Wo; dst = WoT; }
    } else if (bid < 2304) {             // W1: R=1024, C=4096
        const int t = bid - 1280;
        bx = t & 63; by = t >> 6; R = 1024; C = 4096;
        src = W1; dst = W1T;
    } else {                             // W2: R=4096, C=1024
        const int t = bid - 2304;
        bx = t & 15; by = t >> 4; R = 4096; C = 1024;
        src = W2; dst = W2T;
    }

    __shared__ float tile[64][65];
    const int r0 = by * 64, c0 = bx * 64;
    #pragma unroll
    for (int i = 0; i < 4; i++)
        tile[ty + 16 * i][tx] = src[(size_t)(r0 + ty + 16 * i) * C + c0 + tx];
    __syncthreads();
    #pragma unroll
    for (int i = 0; i < 4; i++)
        dst[(size_t)(c0 + ty + 16 * i) * R + r0 + tx] =
            f2bf(tile[tx][ty + 16 * i]);
}

// ---------------------------------------------------------------------------
// Row LayerNorm, wave-per-row: f32 [row][1024] -> bf16 [row][1024].
// 256 thr = 4 waves = 4 rows/block; no __syncthreads; shfl_xor reduce.
// ---------------------------------------------------------------------------
__global__ __launch_bounds__(256) void ln_kernel(
    const float* __restrict__ x, const float* __restrict__ g,
    const float* __restrict__ b, short* __restrict__ y)
{
    const int wave = threadIdx.x >> 6, lane = threadIdx.x & 63;
    const int row  = blockIdx.x * 4 + wave;
    const float4* xr = (const float4*)(x + (size_t)row * D_MODEL);
    float4 v[4];
    float s = 0.0f, ss = 0.0f;
    #pragma unroll
    for (int qq = 0; qq < 4; qq++) {
        v[qq] = xr[lane + qq * 64];
        s  += v[qq].x + v[qq].y + v[qq].z + v[qq].w;
        ss += v[qq].x * v[qq].x + v[qq].y * v[qq].y
            + v[qq].z * v[qq].z + v[qq].w * v[qq].w;
    }
    #pragma unroll
    for (int off = 32; off > 0; off >>= 1) {
        s  += __shfl_xor(s, off);
        ss += __shfl_xor(ss, off);
    }
    const float mu  = s * (1.0f / D_MODEL);
    const float var = ss * (1.0f / D_MODEL) - mu * mu;
    const float rs  = rsqrtf(var + 1e-5f);
    short4v* yr = (short4v*)(y + (size_t)row * D_MODEL);
    #pragma unroll
    for (int qq = 0; qq < 4; qq++) {
        const float4 gg = ((const float4*)g)[lane + qq * 64];
        const float4 bb = ((const float4*)b)[lane + qq * 64];
        short4v o;
        o.x = f2bf((v[qq].x - mu) * rs * gg.x + bb.x);
        o.y = f2bf((v[qq].y - mu) * rs * gg.y + bb.y);
        o.z = f2bf((v[qq].z - mu) * rs * gg.z + bb.z);
        o.w = f2bf((v[qq].w - mu) * rs * gg.w + bb.w);
        yr[lane + qq * 64] = o;
    }
}

// ---------------------------------------------------------------------------
// bf16 MFMA GEMM: C[M][N] = A[M][K](bf16) * BT[N][K](bf16)^T, fused epilogue.
// Block 256 = 4 waves; tile 128x128; wave owns 64x64 as 4x4 of 16x16x32 MFMA.
// Staging: global_load_lds width=16, double-buffered LDS, 1 barrier/iter.
// LDS slot map (16B units): slot(row, q) = row*4 + (q ^ ((row>>1)&3)).
// Grid swizzle: windows of 8 x-blocks, y fastest (R4 measured-best).
// __launch_bounds__(256,4): cap unified regs at 128/wave -> 4 blocks/CU.
// mode 0: out_bf16 = (col>=3072 ? sigmoid : id)(acc + bias)        [QKVG]
// mode 1: out_f32  = acc + bias + res   (res==outf in-place is OK) [x2 / final]
// mode 2: out_bf16 = gelu_exact(acc + bias)                        [FFN mid]
// (EXACT measured-best loop: 226us/big-gemm, VGPR 56, 0 conflicts.)
// ---------------------------------------------------------------------------
__global__ __launch_bounds__(256, 4) void gemm_bf16(
    const short* __restrict__ A, const short* __restrict__ BT,
    const float* __restrict__ bias, const float* __restrict__ res,
    float* __restrict__ outf, short* __restrict__ outb,
    int M, int N, int K, int mode)
{
    __shared__ short As[2 * 4096];   // 2 x 8 KB, slot-swizzled
    __shared__ short Bs[2 * 4096];

    // ---- grid swizzle: window = 8 x-values * all y, y fastest inside ----
    const int gx = gridDim.x, gy = gridDim.y;
    const int lin = blockIdx.x + blockIdx.y * gx;
    const int win = 8 * gy;
    const int grp = lin / win;
    const int rem = lin - grp * win;
    const int bx = grp * 8 + (rem & 7);
    const int by = rem >> 3;

    const int tid  = threadIdx.x;
    const int row0 = bx * 128;
    const int col0 = by * 128;
    const int lane = tid & 63;
    const int wave = tid >> 6;
    const int wm = (wave & 1) << 6;
    const int wn = (wave >> 1) << 6;
    const int lm = lane & 15;            // m / n index within 16-tile
    const int q  = lane >> 4;            // kgroup 0..3 of this lane's fragment

    float4v acc[4][4];
    #pragma unroll
    for (int i = 0; i < 4; i++)
        #pragma unroll
        for (int j = 0; j < 4; j++)
            acc[i][j] = (float4v)(0.0f);

    // ---- staging decode (constant per lane; only k0 varies) ----
    const int s0 = wave * 64 + lane;
    const int s1 = 256 + wave * 64 + lane;
    const int r0 = s0 >> 2, q0 = (s0 & 3) ^ ((r0 >> 1) & 3);
    const int r1 = s1 >> 2, q1 = (s1 & 3) ^ ((r1 >> 1) & 3);
    const short* gA0 = A  + (size_t)(row0 + r0) * K + q0 * 8;
    const short* gA1 = A  + (size_t)(row0 + r1) * K + q1 * 8;
    const short* gB0 = BT + (size_t)(col0 + r0) * K + q0 * 8;
    const short* gB1 = BT + (size_t)(col0 + r1) * K + q1 * 8;
    short* lA0 = As + s0 * 8;
    short* lA1 = As + s1 * 8;
    short* lB0 = Bs + s0 * 8;
    short* lB1 = Bs + s1 * 8;

    // fragment-read swizzle: row = 16*t + lm  ->  (row>>1)&3 == (lm>>1)&3
    const int swz = (lm >> 1) & 3;
    const int qs  = q ^ swz;             // swizzled kgroup slot for reads

    // prologue: tile 0 -> buffer 0
    load_lds16(gA0, lA0);
    load_lds16(gA1, lA1);
    load_lds16(gB0, lB0);
    load_lds16(gB1, lB1);

    int p = 0;
    for (int k0 = 0; k0 < K; k0 += 32) {
        __syncthreads();                 // drains this tile's loads + prior reads
        const int kn = k0 + 32;
        const int po = p ^ 1;
        if (kn < K) {                    // prefetch next tile into other buffer
            load_lds16(gA0 + kn, lA0 + po * 4096);
            load_lds16(gA1 + kn, lA1 + po * 4096);
            load_lds16(gB0 + kn, lB0 + po * 4096);
            load_lds16(gB1 + kn, lB1 + po * 4096);
        }
        const short* Ab = As + p * 4096;
        const short* Bb = Bs + p * 4096;

        short8 af[4], bfr[4];
        #pragma unroll
        for (int i = 0; i < 4; i++)
            af[i] = *(const short8*)&Ab[((wm + i * 16 + lm) * 4 + qs) * 8];
        #pragma unroll
        for (int j = 0; j < 4; j++)
            bfr[j] = *(const short8*)&Bb[((wn + j * 16 + lm) * 4 + qs) * 8];
        #pragma unroll
        for (int i = 0; i < 4; i++)
            #pragma unroll
            for (int j = 0; j < 4; j++)
                acc[i][j] = __builtin_amdgcn_mfma_f32_16x16x32_bf16(
                    af[i], bfr[j], acc[i][j], 0, 0, 0);
        p ^= 1;
    }

    const int r4 = (lane >> 4) << 2;     // C/D: row=(lane>>4)*4+reg, col=lane&15
    #pragma unroll
    for (int i = 0; i < 4; i++) {
        #pragma unroll
        for (int j = 0; j < 4; j++) {
            int colg = col0 + wn + j * 16 + lm;
            float bcol = bias[colg];
            #pragma unroll
            for (int r2 = 0; r2 < 4; r2++) {
                int rowg = row0 + wm + i * 16 + r4 + r2;
                size_t idx = (size_t)rowg * N + colg;
                float v = acc[i][j][r2] + bcol;
                if (mode == 0) {
                    if (colg >= 3072) v = 1.0f / (1.0f + expf(-v));
                    outb[idx] = f2bf(v);
                } else if (mode == 1) {
                    outf[idx] = v + res[idx];
                } else {
                    v = 0.5f * v * (1.0f + erff(v * 0.70710678118654752f));
                    outb[idx] = f2bf(v);
                }
            }
        }
    }
}

// ---------------------------------------------------------------------------
// Retention scan, short2-vectorized (2 channels/thread), CHUNK=64.
// qkvg bf16 [16384][4096]: q|k|v|g sections. channel c = b*1024 + col.
// 512 blocks x 256 thr per pass (TLP preserved); 4B/lane loads.
// pass2 computes sinit inline (Horner over carry[0..j-1]).
// ---------------------------------------------------------------------------
__global__ __launch_bounds__(256) void scan_pass1(
    const short* __restrict__ qkvg, const float* __restrict__ dlogit,
    float* __restrict__ carry)
{
    const int j    = blockIdx.x >> 3;                       // chunk 0..63
    const int p    = ((blockIdx.x & 7) << 8) + threadIdx.x; // 0..2047
    const int col2 = p << 1;
    const int b    = col2 >> 10;
    const int col  = col2 & 1023;
    const float decay = 1.0f / (1.0f + expf(-dlogit[col >> 6]));
    size_t base = ((size_t)b * LSEQ + j * CHUNK) * 4096 + col;
    float s0 = 0.0f, s1 = 0.0f;
    for (int t = 0; t < CHUNK; ++t) {
        short2 kk = *(const short2*)&qkvg[base + 1024];
        short2 vv = *(const short2*)&qkvg[base + 2048];
        s0 = decay * s0 + bf2f(kk.x) * bf2f(vv.x);
        s1 = decay * s1 + bf2f(kk.y) * bf2f(vv.y);
        base += 4096;
    }
    *(float2*)&carry[j * 4096 + col2] = make_float2(s0, s1);
}

__global__ __launch_bounds__(256) void scan_pass2(
    const short* __restrict__ qkvg, const float* __restrict__ dlogit,
    const float* __restrict__ carry, short* __restrict__ att)
{
    const int j    = blockIdx.x >> 3;
    const int p    = ((blockIdx.x & 7) << 8) + threadIdx.x;
    const int col2 = p << 1;
    const int b    = col2 >> 10;
    const int col  = col2 & 1023;
    const float decay = 1.0f / (1.0f + expf(-dlogit[col >> 6]));
    const float dp = powf(decay, (float)CHUNK);
    float s0 = 0.0f, s1 = 0.0f;
    for (int i = 0; i < j; ++i) {        // inline sinit (Horner, same order)
        float2 cc = *(const float2*)&carry[i * 4096 + col2];
        s0 = dp * s0 + cc.x;
        s1 = dp * s1 + cc.y;
    }
    size_t base  = ((size_t)b * LSEQ + j * CHUNK) * 4096 + col;
    size_t obase = ((size_t)b * LSEQ + j * CHUNK) * 1024 + col;
    for (int t = 0; t < CHUNK; ++t) {
        short2 qq = *(const short2*)&qkvg[base];
        short2 kk = *(const short2*)&qkvg[base + 1024];
        short2 vv = *(const short2*)&qkvg[base + 2048];
        short2 gg = *(const short2*)&qkvg[base + 3072];
        s0 = decay * s0 + bf2f(kk.x) * bf2f(vv.x);
        s1 = decay * s1 + bf2f(kk.y) * bf2f(vv.y);
        short2 o;
        o.x = f2bf(bf2f(gg.x) * bf2f(qq.x) * s0 * 0.125f);  // scale = DH^-0.5
        o.y = f2bf(bf2f(gg.y) * bf2f(qq.y) * s1 * 0.125f);
        *(short2*)&att[obase] = o;
        base += 4096; obase += 1024;
    }
}

// ---------------------------------------------------------------------------
extern "C" void kernel_launch(void* const* d_in, const int* in_sizes, int n_in,
                              void* d_out, int out_size, void* d_ws, size_t ws_size,
                              hipStream_t stream)
{
    const float* x      = (const float*)d_in[0];
    const float* ln1_g  = (const float*)d_in[1];
    const float* ln1_b  = (const float*)d_in[2];
    const float* Wq     = (const float*)d_in[3];
    const float* bq     = (const float*)d_in[4];
    const float* Wk     = (const float*)d_in[5];
    const float* bk     = (const float*)d_in[6];
    const float* Wv     = (const float*)d_in[7];
    const float* bv     = (const float*)d_in[8];
    const float* Wg     = (const float*)d_in[9];
    const float* bg     = (const float*)d_in[10];
    const float* dlog   = (const float*)d_in[11];
    const float* Wo     = (const float*)d_in[12];
    const float* bo     = (const float*)d_in[13];
    const float* ln2_g  = (const float*)d_in[14];
    const float* ln2_b  = (const float*)d_in[15];
    const float* W1     = (const float*)d_in[16];
    const float* b1     = (const float*)d_in[17];
    const float* W2     = (const float*)d_in[18];
    const float* b2     = (const float*)d_in[19];
    float* out = (float*)d_out;

    char* ws = (char*)d_ws;
    size_t off = 0;
    auto alloc = [&](size_t bytes) -> void* {
        void* p = ws + off;
        off += (bytes + 255) & ~(size_t)255;
        return p;
    };
    // ---- workspace layout (~196 MB total) ----
    short* WqkvgT = (short*)alloc((size_t)4096 * 1024 * 2);   // 8 MB  [n=4096][k=1024]
    short* WoT    = (short*)alloc((size_t)1024 * 1024 * 2);   // 2 MB  [n=1024][k=1024]
    short* W1T    = (short*)alloc((size_t)4096 * 1024 * 2);   // 8 MB  [n=4096][k=1024]
    short* W2T    = (short*)alloc((size_t)1024 * 4096 * 2);   // 8 MB  [n=1024][k=4096]
    float* biasq  = (float*)alloc((size_t)4096 * 4);
    float* carry  = (float*)alloc((size_t)NCH * 4096 * 4);    // 1 MB
    short* bufA   = (short*)alloc((size_t)NROWS * 1024 * 2);  // 32 MB: y -> att -> h
    short* bufB   = (short*)alloc((size_t)NROWS * 4096 * 2);  // 128 MB: qkvg -> ff1
    // x2 lives in d_out (64 MB saved); final GEMM does in-place residual.
    float* x2 = out;
    short* ybuf = bufA;   // LN1 output
    short* att  = bufA;   // scan output (ybuf dead by then)
    short* hbuf = bufA;   // LN2 output (att dead by then)
    short* qkvg = bufB;
    short* ff1  = bufB;   // qkvg dead after scan_pass2
    (void)in_sizes; (void)n_in; (void)out_size;

    if (off > ws_size) return;  // ws too small: fail validation cleanly, not a segfault

    // prep (7 transposes + bias concat) + LN1 in ONE launch
    prep_ln1<<<4356, 1024, 0, stream>>>(
        Wq, Wk, Wv, Wg, Wo, W1, W2, bq, bk, bv, bg,
        x, ln1_g, ln1_b,
        WqkvgT, WoT, W1T, W2T, biasq, ybuf);

    // QKVG projection (fused bias + sigmoid on G)
    gemm_bf16<<<dim3(128, 32), 256, 0, stream>>>(
        ybuf, WqkvgT, biasq, nullptr, nullptr, qkvg, NROWS, 4096, 1024, 0);

    // retention scan (short2, CHUNK=64; combine folded into pass2)
    scan_pass1<<<NCH * 8, 256, 0, stream>>>(qkvg, dlog, carry);
    scan_pass2<<<NCH * 8, 256, 0, stream>>>(qkvg, dlog, carry, att);

    // output projection + residual: x2 = x + att@Wo + bo   (x2 == d_out)
    gemm_bf16<<<dim3(128, 8), 256, 0, stream>>>(
        att, WoT, bo, x, x2, nullptr, NROWS, 1024, 1024, 1);

    // LN2: x2 -> h(bf16)
    ln_kernel<<<NROWS / 4, 256, 0, stream>>>(x2, ln2_g, ln2_b, hbuf);

    // FFN: ff1 = gelu(h@W1 + b1)  (bf16)
    gemm_bf16<<<dim3(128, 32), 256, 0, stream>>>(
        hbuf, W1T, b1, nullptr, nullptr, ff1, NROWS, 4096, 1024, 2);

    // out = x2 + ff1@W2 + b2   (in-place residual on d_out)
    gemm_bf16<<<dim3(128, 8), 256, 0, stream>>>(
        ff1, W2T, b2, x2, out, nullptr, NROWS, 1024, 4096, 1);
}